// Round 10
// baseline (108.307 us; speedup 1.0000x reference)
//
#include <hip/hip_runtime.h>

// Problem constants (from reference setup_inputs)
#define NTOT  4096    // total nodes
#define NG    64      // graphs (B)
#define NMAXD 128     // N_MAX dense padding
#define HD    64      // hidden dim
#define NEDGE 65536   // edges (and pairs)
#define EPG   (NEDGE / NG)   // 1024 edges per graph
#define NPG   (NTOT / NG)    // 64 nodes per graph

typedef float f4 __attribute__((ext_vector_type(4)));

__device__ __forceinline__ int lowb(const int* __restrict__ batch, int key) {
  int lo = 0, hi = NTOT;                    // first i with batch[i] >= key
  while (lo < hi) { const int mid = (lo + hi) >> 1;
    if (batch[mid] < key) lo = mid + 1; else hi = mid; }
  return lo;
}

// ---------------------------------------------------------------------------
// Dispatch 1: role-split blocks (zeros first so the store stream starts at t=0)
//   [0, 2048):        zero blocks — 2 planes' pad region each (fill-shaped)
//   [2048, 3072):     edge encoder  (64 edges,  K=32) -> valE4[h/4][j] f4
//   [3072, 4096):     pair encoder  (64 pairs,  K=16) -> valP4
//   [4096, 4160):     node encoder  (64 nodes,  K=48) -> valN4
//   4160:             mask + counts
//   [4161, 4689):     rc codes (binary search on sorted batch, L2-hot)
// val4 layout: f4 element = h-group {4*h4..4*h4+3} for item j -> both the
// encoder writes and the scatter reads are perfectly lane-contiguous.
// ---------------------------------------------------------------------------
#define NZBLK 2048
#define ENCE_B (NEDGE / 64)
#define ENCP_B (NEDGE / 64)
#define ENCN_B (NTOT / 64)
#define RC_ITEMS (2 * NEDGE + NTOT)
#define NRCB ((RC_ITEMS + 255) / 256)
#define D1_GRID (NZBLK + ENCE_B + ENCP_B + ENCN_B + 1 + NRCB)
#define SMEM_F (48 * HD + 64 * 49)          // node-enc footprint (max) = 24.8 KB

template <int K>
__device__ __forceinline__ void enc_body(
    const float* __restrict__ x, const float* __restrict__ W,
    f4* __restrict__ val4, int n, int j0, float* smem, int tid) {
  float* Ws = smem;                 // K*HD
  float* xs = smem + K * HD;        // 64*(K+1), +1 pad: conflict-free columns
  for (int idx = tid; idx < K * HD; idx += 256) Ws[idx] = W[idx];
  for (int idx = tid; idx < 64 * K; idx += 256)
    xs[(idx / K) * (K + 1) + (idx % K)] = x[(size_t)j0 * K + idx];
  __syncthreads();
  const int e = tid & 63, hq = tid >> 6;    // 16 h-values per thread
  const int j = j0 + e;
  float acc[16];
#pragma unroll
  for (int t = 0; t < 16; ++t) acc[t] = 0.f;
#pragma unroll
  for (int k = 0; k < K; ++k) {
    const float xv = xs[e * (K + 1) + k];   // Ws read is wave-uniform (bcast)
#pragma unroll
    for (int t = 0; t < 16; ++t) acc[t] += xv * Ws[k * HD + hq * 16 + t];
  }
#pragma unroll
  for (int t4 = 0; t4 < 4; ++t4) {
    f4 v; v.x = acc[t4*4]; v.y = acc[t4*4+1]; v.z = acc[t4*4+2]; v.w = acc[t4*4+3];
    val4[(size_t)(hq * 4 + t4) * n + j] = v;   // lanes j contiguous: coalesced
  }
}

__device__ __forceinline__ void enc_node_body(
    const float* __restrict__ nx, const float* __restrict__ lx,
    const float* __restrict__ Wn, const float* __restrict__ Wl,
    f4* __restrict__ val4, int j0, float* smem, int tid) {
  float* Ws = smem;                 // 48*HD: rows [0:32)=W_node, [32:48)=W_loop
  float* xs = smem + 48 * HD;       // 64*49
  for (int idx = tid; idx < 32 * HD; idx += 256) Ws[idx] = Wn[idx];
  for (int idx = tid; idx < 16 * HD; idx += 256) Ws[32 * HD + idx] = Wl[idx];
  for (int idx = tid; idx < 64 * 32; idx += 256)
    xs[(idx >> 5) * 49 + (idx & 31)] = nx[(size_t)j0 * 32 + idx];
  for (int idx = tid; idx < 64 * 16; idx += 256)
    xs[(idx >> 4) * 49 + 32 + (idx & 15)] = lx[(size_t)j0 * 16 + idx];
  __syncthreads();
  const int e = tid & 63, hq = tid >> 6;
  const int j = j0 + e;
  float acc[16];
#pragma unroll
  for (int t = 0; t < 16; ++t) acc[t] = 0.f;
#pragma unroll
  for (int k = 0; k < 48; ++k) {
    const float xv = xs[e * 49 + k];
#pragma unroll
    for (int t = 0; t < 16; ++t) acc[t] += xv * Ws[k * HD + hq * 16 + t];
  }
#pragma unroll
  for (int t4 = 0; t4 < 4; ++t4) {
    f4 v; v.x = acc[t4*4]; v.y = acc[t4*4+1]; v.z = acc[t4*4+2]; v.w = acc[t4*4+3];
    val4[(size_t)(hq * 4 + t4) * NTOT + j] = v;
  }
}

__global__ __launch_bounds__(256) void d1_kernel(
    const float* __restrict__ node_x, const float* __restrict__ loop_x,
    const float* __restrict__ edge_attr, const float* __restrict__ pair_x,
    const float* __restrict__ Wn, const float* __restrict__ Wl,
    const float* __restrict__ We, const float* __restrict__ Wp,
    const int* __restrict__ eI, const int* __restrict__ pI,
    const int* __restrict__ batch,
    f4* __restrict__ valE4, f4* __restrict__ valP4, f4* __restrict__ valN4,
    int* __restrict__ rcE, int* __restrict__ rcP, int* __restrict__ rcN,
    float* __restrict__ out, float* __restrict__ mask) {
  __shared__ float smem[SMEM_F];
  const int tid = threadIdx.x;
  int b2 = (int)blockIdx.x;

  if (b2 < NZBLK) {
    // ---- streaming zeros: 2 planes' pad region, fill-shaped ----
#pragma unroll
    for (int t = 0; t < 2; ++t) {
      f4* plane = (f4*)(out + (size_t)(b2 * 2 + t) * (NMAXD * NMAXD));
#pragma unroll
      for (int k = 0; k < 8; ++k) plane[2048 + tid + k * 256] = (f4)(0.f);
#pragma unroll
      for (int k = 0; k < 4; ++k) {
        const int i = tid + k * 256;
        plane[(i >> 4) * 32 + 16 + (i & 15)] = (f4)(0.f);
      }
    }
    return;
  }
  b2 -= NZBLK;
  if (b2 < ENCE_B) { enc_body<32>(edge_attr, We, valE4, NEDGE, b2 * 64, smem, tid); return; }
  b2 -= ENCE_B;
  if (b2 < ENCP_B) { enc_body<16>(pair_x, Wp, valP4, NEDGE, b2 * 64, smem, tid); return; }
  b2 -= ENCP_B;
  if (b2 < ENCN_B) { enc_node_body(node_x, loop_x, Wn, Wl, valN4, b2 * 64, smem, tid); return; }
  b2 -= ENCN_B;
  if (b2 == 0) {
    // ---- mask + counts ----
    int* cnts = (int*)smem;
    if (tid < NG) cnts[tid] = lowb(batch, tid + 1) - lowb(batch, tid);
    __syncthreads();
    for (int idx = tid; idx < NG * NMAXD; idx += 256)
      mask[idx] = ((idx & (NMAXD - 1)) < cnts[idx >> 7]) ? 1.0f : 0.0f;
    return;
  }
  b2 -= 1;
  // ---- rc codes ----
  const int i = b2 * 256 + tid;
  if (i < NEDGE) {
    const int n0 = eI[i], n1 = eI[NEDGE + i];
    const int b0 = batch[n0], b1 = batch[n1];
    rcE[i] = (b0 << 16) | ((n0 - lowb(batch, b0)) << 8) | (n1 - lowb(batch, b1));
  } else if (i < 2 * NEDGE) {
    const int j = i - NEDGE;
    const int n0 = pI[j], n1 = pI[NEDGE + j];
    const int b0 = batch[n0], b1 = batch[n1];
    rcP[j] = (b0 << 16) | ((n0 - lowb(batch, b0)) << 8) | (n1 - lowb(batch, b1));
  } else if (i < RC_ITEMS) {
    const int j = i - 2 * NEDGE;
    const int b = batch[j];
    const int p = j - lowb(batch, b);
    rcN[j] = (b << 16) | (p << 8) | p;
  }
}

// ---------------------------------------------------------------------------
// Dispatch 2: scatter. Block = (graph g, h-group h4). 512 thr, 64 KB LDS.
// Per item: 1 coalesced f4 val load + 1 rc load + 4 ds_add_f32. Then write
// only the 64x64 quadrant. All loads lane-contiguous.
// ---------------------------------------------------------------------------
#define BT 512
__global__ __launch_bounds__(BT) void scatter_kernel(
    const f4* __restrict__ valE4, const f4* __restrict__ valP4,
    const f4* __restrict__ valN4,
    const int* __restrict__ rcE, const int* __restrict__ rcP,
    const int* __restrict__ rcN, float* __restrict__ out) {
  __shared__ float acc[4 * 4096];            // 64 KB
  const int tid = threadIdx.x;
  // XCD-aware swizzle: all 16 h4-blocks of graph g on one XCD (d%8 rr)
  const int d  = (int)blockIdx.x;
  const int g  = ((d & 7) << 3) | ((d >> 3) & 7);
  const int h4 = d >> 6;                     // h0 = h4*4

  for (int i = tid; i < 4096; i += BT) ((f4*)acc)[i] = (f4)(0.f);
  __syncthreads();

  // ---- edges: 2 items/thread ----
#pragma unroll
  for (int k = 0; k < 2; ++k) {
    const int j = g * EPG + tid + k * BT;
    const f4 v = valE4[(size_t)h4 * NEDGE + j];
    const int code = rcE[j];
    const int b = code >> 16, r = (code >> 8) & 255, c = code & 255;
    if (b == g && r < 64 && c < 64) {
      const int a = r * 64 + c;
      unsafeAtomicAdd(&acc[a], v.x);          unsafeAtomicAdd(&acc[4096 + a], v.y);
      unsafeAtomicAdd(&acc[8192 + a], v.z);   unsafeAtomicAdd(&acc[12288 + a], v.w);
    } else {  // general fallback (never taken for this input layout)
      unsafeAtomicAdd(&out[(((size_t)b * HD + h4 * 4 + 0) * NMAXD + r) * NMAXD + c], v.x);
      unsafeAtomicAdd(&out[(((size_t)b * HD + h4 * 4 + 1) * NMAXD + r) * NMAXD + c], v.y);
      unsafeAtomicAdd(&out[(((size_t)b * HD + h4 * 4 + 2) * NMAXD + r) * NMAXD + c], v.z);
      unsafeAtomicAdd(&out[(((size_t)b * HD + h4 * 4 + 3) * NMAXD + r) * NMAXD + c], v.w);
    }
  }

  // ---- pairs: 2 items/thread ----
#pragma unroll
  for (int k = 0; k < 2; ++k) {
    const int j = g * EPG + tid + k * BT;
    const f4 v = valP4[(size_t)h4 * NEDGE + j];
    const int code = rcP[j];
    const int b = code >> 16, r = (code >> 8) & 255, c = code & 255;
    if (b == g && r < 64 && c < 64) {
      const int a = r * 64 + c;
      unsafeAtomicAdd(&acc[a], v.x);          unsafeAtomicAdd(&acc[4096 + a], v.y);
      unsafeAtomicAdd(&acc[8192 + a], v.z);   unsafeAtomicAdd(&acc[12288 + a], v.w);
    } else {
      unsafeAtomicAdd(&out[(((size_t)b * HD + h4 * 4 + 0) * NMAXD + r) * NMAXD + c], v.x);
      unsafeAtomicAdd(&out[(((size_t)b * HD + h4 * 4 + 1) * NMAXD + r) * NMAXD + c], v.y);
      unsafeAtomicAdd(&out[(((size_t)b * HD + h4 * 4 + 2) * NMAXD + r) * NMAXD + c], v.z);
      unsafeAtomicAdd(&out[(((size_t)b * HD + h4 * 4 + 3) * NMAXD + r) * NMAXD + c], v.w);
    }
  }

  // ---- nodes: first 64 lanes ----
  if (tid < NPG) {
    const int j = g * NPG + tid;
    const f4 v = valN4[(size_t)h4 * NTOT + j];
    const int code = rcN[j];
    const int b = code >> 16, r = (code >> 8) & 255, c = code & 255;
    if (b == g && r < 64 && c < 64) {
      const int a = r * 64 + c;
      unsafeAtomicAdd(&acc[a], v.x);          unsafeAtomicAdd(&acc[4096 + a], v.y);
      unsafeAtomicAdd(&acc[8192 + a], v.z);   unsafeAtomicAdd(&acc[12288 + a], v.w);
    } else {
      unsafeAtomicAdd(&out[(((size_t)b * HD + h4 * 4 + 0) * NMAXD + r) * NMAXD + c], v.x);
      unsafeAtomicAdd(&out[(((size_t)b * HD + h4 * 4 + 1) * NMAXD + r) * NMAXD + c], v.y);
      unsafeAtomicAdd(&out[(((size_t)b * HD + h4 * 4 + 2) * NMAXD + r) * NMAXD + c], v.z);
      unsafeAtomicAdd(&out[(((size_t)b * HD + h4 * 4 + 3) * NMAXD + r) * NMAXD + c], v.w);
    }
  }
  __syncthreads();

  // ---- write the 64x64 quadrant (rows 0-63, f4-cols 0-15) ----
#pragma unroll
  for (int t = 0; t < 4; ++t) {
    f4* plane = (f4*)(out + ((size_t)g * HD + h4 * 4 + t) * NMAXD * NMAXD);
#pragma unroll
    for (int k = 0; k < 2; ++k) {
      const int idx = tid + k * BT;           // 0..1023
      const int r = idx >> 4, c4 = idx & 15;
      plane[r * 32 + c4] = *(const f4*)&acc[t * 4096 + r * 64 + c4 * 4];
    }
  }
}

// ---------------------------------------------------------------------------
extern "C" void kernel_launch(void* const* d_in, const int* in_sizes, int n_in,
                              void* d_out, int out_size, void* d_ws, size_t ws_size,
                              hipStream_t stream) {
  const float* node_x    = (const float*)d_in[0];
  const float* loop_x    = (const float*)d_in[1];
  const float* edge_attr = (const float*)d_in[2];
  const float* pair_x    = (const float*)d_in[3];
  const float* W_node    = (const float*)d_in[4];
  const float* W_loop    = (const float*)d_in[5];
  const float* W_edge    = (const float*)d_in[6];
  const float* W_pair    = (const float*)d_in[7];
  const int*   batch     = (const int*)d_in[8];
  const int*   edge_index = (const int*)d_in[9];    // [2][E]
  const int*   pair_index = (const int*)d_in[10];   // [2][E]

  float* out  = (float*)d_out;
  float* mask = out + (size_t)NG * HD * NMAXD * NMAXD;

  // ws layout (float units): valE4 | valP4 | valN4 | rcE | rcP | rcN
  float* ws   = (float*)d_ws;
  f4*    valE4 = (f4*)ws;                               // HD*NEDGE floats
  f4*    valP4 = (f4*)(ws + (size_t)HD * NEDGE);        // HD*NEDGE floats
  f4*    valN4 = (f4*)(ws + (size_t)2 * HD * NEDGE);    // HD*NTOT floats
  int*   rcE   = (int*)(ws + (size_t)2 * HD * NEDGE + (size_t)HD * NTOT);
  int*   rcP   = rcE + NEDGE;
  int*   rcN   = rcP + NEDGE;

  d1_kernel<<<D1_GRID, 256, 0, stream>>>(node_x, loop_x, edge_attr, pair_x,
      W_node, W_loop, W_edge, W_pair, edge_index, pair_index, batch,
      valE4, valP4, valN4, rcE, rcP, rcN, out, mask);
  scatter_kernel<<<NG * 16, BT, 0, stream>>>(valE4, valP4, valN4,
      rcE, rcP, rcN, out);
}

// Round 11
// 86.286 us; speedup vs baseline: 1.2552x; 1.2552x over previous
//
#include <hip/hip_runtime.h>

// Problem constants (from reference setup_inputs)
#define NTOT  4096    // total nodes
#define NG    64      // graphs (B)
#define NMAXD 128     // N_MAX dense padding
#define HD    64      // hidden dim
#define NEDGE 65536   // edges (and pairs)
#define EPG   (NEDGE / NG)   // 1024 edges per graph
#define NPG   (NTOT / NG)    // 64 nodes per graph

typedef float f4 __attribute__((ext_vector_type(4)));

// ---------------------------------------------------------------------------
// prep_all: packed (b,r,c) codes for every edge/pair/node via binary search
// on the sorted batch array (16 KB, L2-hot), plus counts[g].
// ---------------------------------------------------------------------------
__device__ __forceinline__ int lowb(const int* __restrict__ batch, int key) {
  int lo = 0, hi = NTOT;                    // first i with batch[i] >= key
  while (lo < hi) { const int mid = (lo + hi) >> 1;
    if (batch[mid] < key) lo = mid + 1; else hi = mid; }
  return lo;
}

__global__ __launch_bounds__(256) void prep_all_kernel(
    const int* __restrict__ eI, const int* __restrict__ pI,
    const int* __restrict__ batch,
    int* __restrict__ rcE, int* __restrict__ rcP, int* __restrict__ rcN,
    int* __restrict__ counts) {
  const int i = blockIdx.x * 256 + threadIdx.x;
  if (i < NEDGE) {
    const int n0 = eI[i], n1 = eI[NEDGE + i];
    const int b0 = batch[n0], b1 = batch[n1];
    rcE[i] = (b0 << 16) | ((n0 - lowb(batch, b0)) << 8) | (n1 - lowb(batch, b1));
  } else if (i < 2 * NEDGE) {
    const int j = i - NEDGE;
    const int n0 = pI[j], n1 = pI[NEDGE + j];
    const int b0 = batch[n0], b1 = batch[n1];
    rcP[j] = (b0 << 16) | ((n0 - lowb(batch, b0)) << 8) | (n1 - lowb(batch, b1));
  } else if (i < 2 * NEDGE + NTOT) {
    const int j = i - 2 * NEDGE;
    const int b = batch[j];
    const int p = j - lowb(batch, b);
    rcN[j] = (b << 16) | (p << 8) | p;
  } else if (i < 2 * NEDGE + NTOT + NG) {
    const int g = i - 2 * NEDGE - NTOT;
    counts[g] = lowb(batch, g + 1) - lowb(batch, g);
  }
}

// ---------------------------------------------------------------------------
// Fused encode + scatter + dense write, WAVE-SPECIALIZED.
// Block = (graph g, h-quad of 4). 512 threads (8 waves), 64 KB LDS -> 2/CU.
//   waves 4-7: stream the 192 KB zero region (no phase-1 dep) + mask
//   waves 0-3: projections with k4-OUTER loop (W hoisted to registers,
//              4 items share each W read -> 4x less LDS broadcast traffic)
//              + unsafeAtomicAdd (ds_add_f32) into the 64 KB accumulator
//   barrier; all waves write the 64x64 quadrant.
// ---------------------------------------------------------------------------
#define HQ 4
#define SCT 512
__global__ __launch_bounds__(SCT) void fused_scatter_kernel(
    const float* __restrict__ node_x, const float* __restrict__ loop_x,
    const float* __restrict__ edge_attr, const float* __restrict__ pair_x,
    const float* __restrict__ Wn, const float* __restrict__ Wl,
    const float* __restrict__ We, const float* __restrict__ Wp,
    const int* __restrict__ rcE, const int* __restrict__ rcP,
    const int* __restrict__ rcN, const int* __restrict__ counts,
    float* __restrict__ out, float* __restrict__ mask) {
  __shared__ float acc[HQ * 4096];           // 64 KB accumulator
  __shared__ f4 WcE[32];                     // W_edge[:, h0:h0+4]
  __shared__ f4 WcP[16];                     // W_pair[:, h0:h0+4]
  __shared__ f4 WcN[48];                     // [0:32)=W_node, [32:48)=W_loop

  const int tid = threadIdx.x;
  // XCD-aware swizzle: all 16 hq-blocks of graph g on one XCD (d%8 rr)
  const int d  = (int)blockIdx.x;
  const int g  = ((d & 7) << 3) | ((d >> 3) & 7);
  const int h0 = (d >> 6) * HQ;

  if (tid < 32)       WcE[tid]            = *(const f4*)&We[tid * HD + h0];
  else if (tid < 48)  WcP[tid - 32]       = *(const f4*)&Wp[(tid - 32) * HD + h0];
  else if (tid < 80)  WcN[tid - 48]       = *(const f4*)&Wn[(tid - 48) * HD + h0];
  else if (tid < 96)  WcN[32 + tid - 80]  = *(const f4*)&Wl[(tid - 80) * HD + h0];
  for (int i = tid; i < HQ * 1024; i += SCT) ((f4*)acc)[i] = (f4)(0.f);
  __syncthreads();

  const int wid = tid >> 6;
  if (wid >= 4) {
    // ================= store waves: zero region (192 KB) =================
    const int tz = tid - 256;   // 0..255
#pragma unroll
    for (int t = 0; t < HQ; ++t) {
      f4* plane = (f4*)(out + ((size_t)g * HD + h0 + t) * NMAXD * NMAXD);
      // rows 0-63, f4-cols 16-31 (right half of top rows): 1024 f4
#pragma unroll
      for (int k = 0; k < 4; ++k) {
        const int idx = tz + k * 256;
        plane[(idx >> 4) * 32 + 16 + (idx & 15)] = (f4)(0.f);
      }
      // rows 64-127 full width: 2048 f4 (contiguous tail half of plane)
#pragma unroll
      for (int k = 0; k < 8; ++k)
        plane[2048 + tz + k * 256] = (f4)(0.f);
    }
    if (h0 == 0) {
      const int cg = counts[g];
      for (int i = tz; i < NMAXD; i += 256)
        mask[(size_t)g * NMAXD + i] = (i < cg) ? 1.0f : 0.0f;
    }
  } else {
    // ================= accumulate waves (lanes 0..255) =================
    const int la = tid;

    // ---- edges (K=32): 4 items/thread, k4-OUTER, W hoisted ----
    {
      f4 av[4];
#pragma unroll
      for (int i = 0; i < 4; ++i) av[i] = (f4)(0.f);
      const f4* xr0 = (const f4*)(edge_attr + (size_t)(g * EPG + la) * 32);
#pragma unroll
      for (int k4 = 0; k4 < 8; ++k4) {
        const f4 w0 = WcE[k4 * 4 + 0], w1 = WcE[k4 * 4 + 1];
        const f4 w2 = WcE[k4 * 4 + 2], w3 = WcE[k4 * 4 + 3];
#pragma unroll
        for (int i = 0; i < 4; ++i) {
          const f4 x = xr0[(size_t)i * 256 * 8 + k4];   // item la + i*256
          av[i] += x.x * w0 + x.y * w1 + x.z * w2 + x.w * w3;
        }
      }
#pragma unroll
      for (int i = 0; i < 4; ++i) {
        const int j = g * EPG + la + i * 256;
        const int code = rcE[j];
        const int b = code >> 16, r = (code >> 8) & 255, c = code & 255;
        if (b == g && r < 64 && c < 64) {
          const int a = r * 64 + c;
          unsafeAtomicAdd(&acc[a], av[i].x);          unsafeAtomicAdd(&acc[4096 + a], av[i].y);
          unsafeAtomicAdd(&acc[8192 + a], av[i].z);   unsafeAtomicAdd(&acc[12288 + a], av[i].w);
        } else {  // general fallback (never taken for this input layout)
          unsafeAtomicAdd(&out[(((size_t)b * HD + h0 + 0) * NMAXD + r) * NMAXD + c], av[i].x);
          unsafeAtomicAdd(&out[(((size_t)b * HD + h0 + 1) * NMAXD + r) * NMAXD + c], av[i].y);
          unsafeAtomicAdd(&out[(((size_t)b * HD + h0 + 2) * NMAXD + r) * NMAXD + c], av[i].z);
          unsafeAtomicAdd(&out[(((size_t)b * HD + h0 + 3) * NMAXD + r) * NMAXD + c], av[i].w);
        }
      }
    }

    // ---- pairs (K=16): 4 items/thread, k4-OUTER, W hoisted ----
    {
      f4 av[4];
#pragma unroll
      for (int i = 0; i < 4; ++i) av[i] = (f4)(0.f);
      const f4* xr0 = (const f4*)(pair_x + (size_t)(g * EPG + la) * 16);
#pragma unroll
      for (int k4 = 0; k4 < 4; ++k4) {
        const f4 w0 = WcP[k4 * 4 + 0], w1 = WcP[k4 * 4 + 1];
        const f4 w2 = WcP[k4 * 4 + 2], w3 = WcP[k4 * 4 + 3];
#pragma unroll
        for (int i = 0; i < 4; ++i) {
          const f4 x = xr0[(size_t)i * 256 * 4 + k4];   // item la + i*256
          av[i] += x.x * w0 + x.y * w1 + x.z * w2 + x.w * w3;
        }
      }
#pragma unroll
      for (int i = 0; i < 4; ++i) {
        const int j = g * EPG + la + i * 256;
        const int code = rcP[j];
        const int b = code >> 16, r = (code >> 8) & 255, c = code & 255;
        if (b == g && r < 64 && c < 64) {
          const int a = r * 64 + c;
          unsafeAtomicAdd(&acc[a], av[i].x);          unsafeAtomicAdd(&acc[4096 + a], av[i].y);
          unsafeAtomicAdd(&acc[8192 + a], av[i].z);   unsafeAtomicAdd(&acc[12288 + a], av[i].w);
        } else {
          unsafeAtomicAdd(&out[(((size_t)b * HD + h0 + 0) * NMAXD + r) * NMAXD + c], av[i].x);
          unsafeAtomicAdd(&out[(((size_t)b * HD + h0 + 1) * NMAXD + r) * NMAXD + c], av[i].y);
          unsafeAtomicAdd(&out[(((size_t)b * HD + h0 + 2) * NMAXD + r) * NMAXD + c], av[i].z);
          unsafeAtomicAdd(&out[(((size_t)b * HD + h0 + 3) * NMAXD + r) * NMAXD + c], av[i].w);
        }
      }
    }

    // ---- nodes (K=48 = node_x 32 + loop_x 16), diagonal targets ----
    if (la < NPG) {
      const int j = g * NPG + la;
      const f4* xr = (const f4*)(node_x + (size_t)j * 32);
      const f4* lr = (const f4*)(loop_x + (size_t)j * 16);
      f4 d4 = (f4)(0.f);
#pragma unroll
      for (int k4 = 0; k4 < 8; ++k4) {
        const f4 x = xr[k4];
        d4 += x.x * WcN[k4 * 4 + 0] + x.y * WcN[k4 * 4 + 1]
            + x.z * WcN[k4 * 4 + 2] + x.w * WcN[k4 * 4 + 3];
      }
#pragma unroll
      for (int k4 = 0; k4 < 4; ++k4) {
        const f4 x = lr[k4];
        d4 += x.x * WcN[32 + k4 * 4 + 0] + x.y * WcN[32 + k4 * 4 + 1]
            + x.z * WcN[32 + k4 * 4 + 2] + x.w * WcN[32 + k4 * 4 + 3];
      }
      const int code = rcN[j];
      const int b = code >> 16, r = (code >> 8) & 255, c = code & 255;
      if (b == g && r < 64 && c < 64) {
        const int a = r * 64 + c;
        unsafeAtomicAdd(&acc[a], d4.x);          unsafeAtomicAdd(&acc[4096 + a], d4.y);
        unsafeAtomicAdd(&acc[8192 + a], d4.z);   unsafeAtomicAdd(&acc[12288 + a], d4.w);
      } else {
        unsafeAtomicAdd(&out[(((size_t)b * HD + h0 + 0) * NMAXD + r) * NMAXD + c], d4.x);
        unsafeAtomicAdd(&out[(((size_t)b * HD + h0 + 1) * NMAXD + r) * NMAXD + c], d4.y);
        unsafeAtomicAdd(&out[(((size_t)b * HD + h0 + 2) * NMAXD + r) * NMAXD + c], d4.z);
        unsafeAtomicAdd(&out[(((size_t)b * HD + h0 + 3) * NMAXD + r) * NMAXD + c], d4.w);
      }
    }
  }
  __syncthreads();

  // ---- all waves: write the 64x64 quadrant (rows 0-63, f4-cols 0-15) ----
#pragma unroll
  for (int t = 0; t < HQ; ++t) {
    f4* plane = (f4*)(out + ((size_t)g * HD + h0 + t) * NMAXD * NMAXD);
#pragma unroll
    for (int k = 0; k < 2; ++k) {
      const int idx = tid + k * SCT;           // 0..1023
      const int r = idx >> 4, c4 = idx & 15;
      plane[r * 32 + c4] = *(const f4*)&acc[t * 4096 + r * 64 + c4 * 4];
    }
  }
}

// ---------------------------------------------------------------------------
extern "C" void kernel_launch(void* const* d_in, const int* in_sizes, int n_in,
                              void* d_out, int out_size, void* d_ws, size_t ws_size,
                              hipStream_t stream) {
  const float* node_x    = (const float*)d_in[0];
  const float* loop_x    = (const float*)d_in[1];
  const float* edge_attr = (const float*)d_in[2];
  const float* pair_x    = (const float*)d_in[3];
  const float* W_node    = (const float*)d_in[4];
  const float* W_loop    = (const float*)d_in[5];
  const float* W_edge    = (const float*)d_in[6];
  const float* W_pair    = (const float*)d_in[7];
  const int*   batch     = (const int*)d_in[8];
  const int*   edge_index = (const int*)d_in[9];    // [2][E]
  const int*   pair_index = (const int*)d_in[10];   // [2][E]

  float* out  = (float*)d_out;
  float* mask = out + (size_t)NG * HD * NMAXD * NMAXD;

  // ws layout (int units): rcE | rcP | rcN | counts
  int* rcE    = (int*)d_ws;
  int* rcP    = rcE + NEDGE;
  int* rcN    = rcP + NEDGE;
  int* counts = rcN + NTOT;

  const int prep_items = 2 * NEDGE + NTOT + NG;
  prep_all_kernel<<<(prep_items + 255) / 256, 256, 0, stream>>>(
      edge_index, pair_index, batch, rcE, rcP, rcN, counts);
  fused_scatter_kernel<<<NG * 16, SCT, 0, stream>>>(node_x, loop_x, edge_attr,
      pair_x, W_node, W_loop, W_edge, W_pair, rcE, rcP, rcN, counts, out, mask);
}